// Round 2
// baseline (7699.232 us; speedup 1.0000x reference)
//
#include <hip/hip_runtime.h>

// Farthest Point Sampling: B=16 batches, N=65536 points, S=2048 samples.
// Output: gathered coords (B, S, 3) fp32.
//
// Round-2 design: 16 blocks/batch x 256 threads, 16 register-resident points
// per thread. NO barriers, NO LDS. Each batch has 64 waves = 64 slots in d_ws.
// Per iteration, each wave: register distance+min update -> intra-wave
// butterfly max -> lane 0 publishes (val|inv_idx|seq) to its slot (agent
// scope) -> all 64 lanes poll the 64 slots (lane i polls slot i, coalesced)
// -> per-lane candidate-coord prefetch (hidden behind the second butterfly)
// -> 64-slot butterfly max -> ballot-located winner lane broadcasts coords
// via 3 shuffles. Seq-tagged parity double-buffer: poison 0xAAAA never
// matches seq 1..2048, so no workspace init; skew bound <= 1 iteration.
//
// Arithmetic matches numpy bit-exactly: no FMA (__f*_rn), sum order
// ((dx*dx+dy*dy)+dz*dz), fminf, first-occurrence argmax via inverted-index
// packed key (validated round 1: absmax 0.0).

#define BATCHES 16
#define NPTS    65536
#define NSAMP   2048
#define PB      16                    // blocks per batch
#define TPB     256                   // threads per block
#define WPB     (TPB / 64)            // 4 waves per block
#define SLOTS   (PB * WPB)            // 64 slots per batch
#define PPT     (NPTS / (PB * TPB))   // 16 points per thread

__global__ __launch_bounds__(TPB) void fps_kernel(
    const float* __restrict__ coords,
    float* __restrict__ out,
    unsigned long long* __restrict__ slots) {
  const int blk  = blockIdx.x;
  const int b    = blk >> 4;    // batch
  const int r    = blk & 15;    // rank within batch
  const int t    = threadIdx.x;
  const int lane = t & 63;
  const int wave = t >> 6;
  const int slot_id = r * WPB + wave;

  const float* __restrict__ cb = coords + (size_t)b * NPTS * 3;
  const int base = r * (TPB * PPT);

  // Register-resident points and closest-distance array (~64 data VGPRs).
  float px[PPT], py[PPT], pz[PPT], cl[PPT];
#pragma unroll
  for (int k = 0; k < PPT; ++k) {
    int idx = base + k * TPB + t;
    px[k] = cb[3 * idx + 0];
    py[k] = cb[3 * idx + 1];
    pz[k] = cb[3 * idx + 2];
    cl[k] = __builtin_inff();
  }

  // Initial selected point: index 0 (matches reference).
  float sx = cb[0], sy = cb[1], sz = cb[2];

  for (int it = 0; it < NSAMP; ++it) {
    // --- distance update + per-thread argmax (ascending idx => '>' keeps
    // first occurrence within thread) ---
    float bestv = -1.0f;
    int bestk = 0;
#pragma unroll
    for (int k = 0; k < PPT; ++k) {
      float dx = __fsub_rn(sx, px[k]);
      float dy = __fsub_rn(sy, py[k]);
      float dz = __fsub_rn(sz, pz[k]);
      float d  = __fadd_rn(__fadd_rn(__fmul_rn(dx, dx), __fmul_rn(dy, dy)),
                           __fmul_rn(dz, dz));
      float c  = fminf(cl[k], d);
      cl[k] = c;
      if (c > bestv) { bestv = c; bestk = k; }
    }
    int bestidx = base + bestk * TPB + t;
    // Packed key: monotonic float bits (distances >= 0) | inverted index
    // (ties -> smallest index = numpy first occurrence).
    unsigned long long key =
        ((unsigned long long)__float_as_uint(bestv) << 32) |
        (unsigned long long)(65535 - bestidx);

    // --- intra-wave butterfly max ---
#pragma unroll
    for (int off = 32; off > 0; off >>= 1) {
      unsigned long long o = __shfl_xor(key, off, 64);
      if (o > key) key = o;
    }

    // --- wave leader publishes (val32 | inv_idx16 | seq16) ---
    const int p = (it + 1) & 1;  // parity double-buffer
    unsigned long long* bs = slots + ((size_t)(p * BATCHES + b)) * SLOTS;
    if (lane == 0) {
      unsigned long long sv = (key & 0xFFFFFFFF00000000ull) |
                              ((key & 0xFFFFull) << 16) |
                              (unsigned long long)(it + 1);
      __hip_atomic_store(bs + slot_id, sv, __ATOMIC_RELAXED,
                         __HIP_MEMORY_SCOPE_AGENT);
    }

    // --- every lane polls its own slot (coalesced 512 B per wave) ---
    const unsigned long long want = (unsigned long long)(it + 1);
    unsigned long long v;
    do {
      v = __hip_atomic_load(bs + lane, __ATOMIC_RELAXED,
                            __HIP_MEMORY_SCOPE_AGENT);
    } while ((v & 0xFFFFull) != want);
    unsigned long long k48 = v >> 16;  // valbits(32) . inv_idx(16)

    // Prefetch this slot's candidate coords; hidden behind the butterfly.
    int ci = 65535 - (int)(k48 & 0xFFFFull);
    float gx = cb[3 * ci + 0];
    float gy = cb[3 * ci + 1];
    float gz = cb[3 * ci + 2];

    // --- 64-slot butterfly max ---
    unsigned long long m = k48;
#pragma unroll
    for (int off = 32; off > 0; off >>= 1) {
      unsigned long long o = __shfl_xor(m, off, 64);
      if (o > m) m = o;
    }

    // Winner lane is unique (disjoint index ranges -> unique inv_idx).
    unsigned long long mask = __ballot(k48 == m);
    int src = __ffsll((unsigned long long)mask) - 1;
    sx = __shfl(gx, src, 64);
    sy = __shfl(gy, src, 64);
    sz = __shfl(gz, src, 64);

    if (r == 0 && wave == 0 && lane == 0) {
      float* op = out + ((size_t)b * NSAMP + it) * 3;
      op[0] = sx; op[1] = sy; op[2] = sz;
    }
  }
}

extern "C" void kernel_launch(void* const* d_in, const int* in_sizes, int n_in,
                              void* d_out, int out_size, void* d_ws,
                              size_t ws_size, hipStream_t stream) {
  const float* coords = (const float*)d_in[0];  // (16, 65536, 3) fp32
  // d_in[1] (features) is unused by the reference output.
  float* out = (float*)d_out;                   // (16, 2048, 3) fp32
  unsigned long long* slots = (unsigned long long*)d_ws;  // 2*16*64*8 = 16 KiB
  fps_kernel<<<dim3(BATCHES * PB), dim3(TPB), 0, stream>>>(coords, out, slots);
}

// Round 3
// 3729.882 us; speedup vs baseline: 2.0642x; 2.0642x over previous
//
#include <hip/hip_runtime.h>

// Farthest Point Sampling: B=16 batches, N=65536 points, S=2048 samples.
// Output: gathered coords (B, S, 3) fp32.
//
// Round-3 design = round-1 structure (16 blocks/batch x 256 thr, 16
// register-resident points/thread, 1 polling wave per block, 16 seq-tagged
// parity slots per batch) with the u64 shuffle butterflies (~800 cy each,
// ds_bpermute chains) replaced by DPP reductions on the VALU pipe:
//   - intra-wave: 6-stage DPP f32 value max -> readlane(63); then 6-stage
//     DPP u32 max over (tied ? 0x20000-idx : 0) for exact first-occurrence
//     tie-break (identity 0 is safe: real entries >= 0x10001).
//   - slot reduce: 4-stage DPP u64 max within the row of 16 poller lanes.
// Agent-scope poll traffic stays at round-1 levels (round-2 lesson: polling
// is uncached past L2; keep #pollers x #slots minimal).
//
// Arithmetic matches numpy bit-exactly: no FMA (__f*_rn), sum order
// ((dx*dx+dy*dy)+dz*dz), fminf, first-occurrence argmax (round 1: absmax 0.0).

#define BATCHES 16
#define NPTS    65536
#define NSAMP   2048
#define PB      16                    // blocks per batch
#define TPB     256                   // threads per block
#define WPB     (TPB / 64)            // 4 waves per block
#define PPT     (NPTS / (PB * TPB))   // 16 points per thread

// DPP ctrl codes: 0xB1 quad_perm[1,0,3,2] (xor1), 0x4E quad_perm[2,3,0,1]
// (xor2), 0x141 row_half_mirror (8), 0x140 row_mirror (16),
// 0x142 row_bcast15 (32), 0x143 row_bcast31 (64).

template <int CTRL>
__device__ __forceinline__ float dppmax_f(float x) {
  int y = __builtin_amdgcn_update_dpp(0, __float_as_int(x), CTRL, 0xF, 0xF, true);
  float yf = __int_as_float(y);
  return x > yf ? x : yf;  // distances >= 0 so bound_ctrl 0-fill is identity
}

template <int CTRL>
__device__ __forceinline__ unsigned dppmax_u(unsigned x) {
  unsigned y = (unsigned)__builtin_amdgcn_update_dpp(0, (int)x, CTRL, 0xF, 0xF, true);
  return x > y ? x : y;
}

template <int CTRL>
__device__ __forceinline__ unsigned long long dppmax_u64(unsigned long long x) {
  unsigned lo = (unsigned)x, hi = (unsigned)(x >> 32);
  unsigned plo = (unsigned)__builtin_amdgcn_update_dpp(0, (int)lo, CTRL, 0xF, 0xF, true);
  unsigned phi = (unsigned)__builtin_amdgcn_update_dpp(0, (int)hi, CTRL, 0xF, 0xF, true);
  unsigned long long p = ((unsigned long long)phi << 32) | plo;
  return p > x ? p : x;
}

__global__ __launch_bounds__(TPB) void fps_kernel(
    const float* __restrict__ coords,
    float* __restrict__ out,
    unsigned long long* __restrict__ slots) {
  const int blk  = blockIdx.x;
  const int b    = blk >> 4;    // batch
  const int r    = blk & 15;    // rank within batch
  const int t    = threadIdx.x;
  const int lane = t & 63;
  const int wave = t >> 6;

  const float* __restrict__ cb = coords + (size_t)b * NPTS * 3;
  const int base = r * (TPB * PPT);

  // Register-resident points and closest-distance array (~64 data VGPRs).
  float px[PPT], py[PPT], pz[PPT], cl[PPT];
#pragma unroll
  for (int k = 0; k < PPT; ++k) {
    int idx = base + k * TPB + t;
    px[k] = cb[3 * idx + 0];
    py[k] = cb[3 * idx + 1];
    pz[k] = cb[3 * idx + 2];
    cl[k] = __builtin_inff();
  }

  __shared__ unsigned long long s_wred[WPB];
  __shared__ float s_x, s_y, s_z;

  // Initial selected point: index 0 (matches reference).
  float sx = cb[0], sy = cb[1], sz = cb[2];

  for (int it = 0; it < NSAMP; ++it) {
    // --- distance update + per-thread argmax (ascending idx => '>' keeps
    // first occurrence within thread) ---
    float bestv = -1.0f;
    int bestk = 0;
#pragma unroll
    for (int k = 0; k < PPT; ++k) {
      float dx = __fsub_rn(sx, px[k]);
      float dy = __fsub_rn(sy, py[k]);
      float dz = __fsub_rn(sz, pz[k]);
      float d  = __fadd_rn(__fadd_rn(__fmul_rn(dx, dx), __fmul_rn(dy, dy)),
                           __fmul_rn(dz, dz));
      float c  = fminf(cl[k], d);
      cl[k] = c;
      if (c > bestv) { bestv = c; bestk = k; }
    }
    int bestidx = base + bestk * TPB + t;

    // --- intra-wave value max via DPP (VALU pipe, ~30 cy) ---
    float v = bestv;
    v = dppmax_f<0xB1>(v);
    v = dppmax_f<0x4E>(v);
    v = dppmax_f<0x141>(v);
    v = dppmax_f<0x140>(v);
    v = dppmax_f<0x142>(v);
    v = dppmax_f<0x143>(v);
    v = __int_as_float(__builtin_amdgcn_readlane(__float_as_int(v), 63));

    // --- first-occurrence index among value-tied lanes: u32 max over
    // inverted index (identity 0 never wins; entries in [0x10001,0x20000]) ---
    unsigned inv = (bestv == v) ? (unsigned)(0x20000 - bestidx) : 0u;
    inv = dppmax_u<0xB1>(inv);
    inv = dppmax_u<0x4E>(inv);
    inv = dppmax_u<0x141>(inv);
    inv = dppmax_u<0x140>(inv);
    inv = dppmax_u<0x142>(inv);
    inv = dppmax_u<0x143>(inv);
    int widx = 0x20000 - (int)(unsigned)__builtin_amdgcn_readlane((int)inv, 63);

    // Packed wave key: monotonic float bits | inverted index (ties ->
    // smallest index = numpy first occurrence).
    unsigned long long key =
        ((unsigned long long)__float_as_uint(v) << 32) |
        (unsigned long long)(65535 - widx);

    if (lane == 0) s_wred[wave] = key;
    __syncthreads();

    const int p = (it + 1) & 1;  // parity double-buffer
    unsigned long long* bs = slots + ((size_t)(p * BATCHES + b)) * PB;

    // --- block winner -> publish slot (val32 | inv_idx16 | seq16) ---
    if (t == 0) {
      unsigned long long bk = s_wred[0];
#pragma unroll
      for (int w = 1; w < WPB; ++w) {
        unsigned long long o = s_wred[w];
        if (o > bk) bk = o;
      }
      unsigned long long slotval = (bk & 0xFFFFFFFF00000000ull) |
                                   ((bk & 0xFFFFull) << 16) |
                                   (unsigned long long)(it + 1);
      __hip_atomic_store(bs + r, slotval, __ATOMIC_RELAXED,
                         __HIP_MEMORY_SCOPE_AGENT);
    }

    // --- wave 0, lanes 0-15: poll peers, prefetch coords, DPP-reduce ---
    if (wave == 0 && lane < PB) {
      const unsigned long long want = (unsigned long long)(it + 1);
      unsigned long long sv;
      do {
        sv = __hip_atomic_load(bs + lane, __ATOMIC_RELAXED,
                               __HIP_MEMORY_SCOPE_AGENT);
      } while ((sv & 0xFFFFull) != want);

      // Prefetch this slot's candidate coords; hidden behind the reduce.
      int ci = 65535 - (int)((sv >> 16) & 0xFFFFull);
      float gx = cb[3 * ci + 0];
      float gy = cb[3 * ci + 1];
      float gz = cb[3 * ci + 2];

      // 16-lane u64 max via 4 DPP stages (seq bits equal -> tie-free).
      unsigned long long m = sv;
      m = dppmax_u64<0xB1>(m);
      m = dppmax_u64<0x4E>(m);
      m = dppmax_u64<0x141>(m);
      m = dppmax_u64<0x140>(m);

      // Winner lane is unique (disjoint index ranges -> unique inv_idx).
      if (sv == m) {
        s_x = gx; s_y = gy; s_z = gz;
        if (r == 0) {
          float* op = out + ((size_t)b * NSAMP + it) * 3;
          op[0] = gx; op[1] = gy; op[2] = gz;
        }
      }
    }
    __syncthreads();
    sx = s_x; sy = s_y; sz = s_z;
  }
}

extern "C" void kernel_launch(void* const* d_in, const int* in_sizes, int n_in,
                              void* d_out, int out_size, void* d_ws,
                              size_t ws_size, hipStream_t stream) {
  const float* coords = (const float*)d_in[0];  // (16, 65536, 3) fp32
  // d_in[1] (features) is unused by the reference output.
  float* out = (float*)d_out;                   // (16, 2048, 3) fp32
  unsigned long long* slots = (unsigned long long*)d_ws;  // 2*16*16*8 = 4 KiB
  fps_kernel<<<dim3(BATCHES * PB), dim3(TPB), 0, stream>>>(coords, out, slots);
}